// Round 16
// baseline (835.170 us; speedup 1.0000x reference)
//
#include <hip/hip_runtime.h>
#include <hip/hip_fp16.h>
#include <math.h>

#define NNODES 100000
#define NEDGES 1600000
#define NGRAPH 256
#define NCONV  3
#define TBL    4096
#define CHUNK  512
#define NCHUNK 196         // ceil(100000/512)
#define R_MIN_ 1.0f
#define R_MAX_ 6.0f

typedef float v2f __attribute__((ext_vector_type(2)));

__device__ __forceinline__ float softplus_f(float x){
  return fmaxf(x, 0.f) + __logf(1.f + __expf(-fabsf(x)));
}
__device__ __forceinline__ float sigmoid_f(float x){
  return __builtin_amdgcn_rcpf(1.f + __expf(-x));
}
__device__ __forceinline__ void fma4(float4& a, float s, const float4 w){
  a.x = fmaf(s, w.x, a.x); a.y = fmaf(s, w.y, a.y);
  a.z = fmaf(s, w.z, a.z); a.w = fmaf(s, w.w, a.w);
}
// nontemporal int2 via 64-bit scalar (builtin rejects HIP_vector_type)
__device__ __forceinline__ int2 ntload_i2(const int2* p){
  long long v = __builtin_nontemporal_load((const long long*)p);
  int2 r; r.x = (int)(unsigned)(v & 0xffffffffLL); r.y = (int)(v >> 32);
  return r;
}
__device__ __forceinline__ void ntstore_i2(int2* p, int2 v){
  long long w = (long long)(unsigned)v.x | ((long long)v.y << 32);
  __builtin_nontemporal_store(w, (long long*)p);
}

// ---------------- init: zero chunk counters + graph accumulators ----------------
__global__ void k_init(int* ccnt, float* gsum, int* gcnt){
  int i = blockIdx.x*256 + threadIdx.x;
  if (i < 256) ccnt[i] = 0;
  if (i < NGRAPH){ gsum[i] = 0.f; gcnt[i] = 0; }
}

// ---------------- chunk count ----------------
__global__ void k_cnt(const int* __restrict__ src, int* ccnt){
  __shared__ int l[NCHUNK];
  int t = threadIdx.x;
  int e0 = blockIdx.x * 2048;
  if (t < NCHUNK) l[t] = 0;
  __syncthreads();
  #pragma unroll
  for (int k = 0; k < 8; k++){
    int e = e0 + k*256 + t;
    if (e < NEDGES) atomicAdd(&l[src[e] / CHUNK], 1);
  }
  __syncthreads();
  if (t < NCHUNK && l[t] > 0) atomicAdd(&ccnt[t], l[t]);
}

// ---------------- chunk scan ----------------
__global__ void k_cscan(const int* __restrict__ ccnt, int* __restrict__ cbase,
                        int* __restrict__ ccur, int* __restrict__ offs){
  int t = threadIdx.x;
  if (t == 0){
    int run = 0;
    for (int c = 0; c < NCHUNK; c++){ cbase[c] = run; run += ccnt[c]; }
    cbase[NCHUNK] = NEDGES;
    offs[NNODES] = NEDGES;
  }
  __syncthreads();
  if (t < NCHUNK) ccur[t] = cbase[t];
}

// ---------------- pass 1: bin edges by 512-node chunk ----------------
__global__ void k_bin(const int* __restrict__ src, const int* __restrict__ tgt,
                      const float* __restrict__ elen, int* ccur,
                      int2* __restrict__ eb){
  __shared__ int lcnt[NCHUNK];
  __shared__ int lbase[NCHUNK];
  __shared__ int loff[NCHUNK];
  int t = threadIdx.x;
  int e0 = blockIdx.x * 2048;
  if (t < NCHUNK){ lcnt[t] = 0; loff[t] = 0; }
  __syncthreads();
  #pragma unroll
  for (int k = 0; k < 8; k++){
    int e = e0 + k*256 + t;
    if (e < NEDGES) atomicAdd(&lcnt[src[e] / CHUNK], 1);
  }
  __syncthreads();
  if (t < NCHUNK && lcnt[t] > 0) lbase[t] = atomicAdd(&ccur[t], lcnt[t]);
  __syncthreads();
  #pragma unroll
  for (int k = 0; k < 8; k++){
    int e = e0 + k*256 + t;
    if (e < NEDGES){
      int s = src[e];
      int c = s / CHUNK;
      int r = atomicAdd(&loff[c], 1);
      float key = (elen[e] - R_MIN_) * ((float)(TBL-1)/(R_MAX_-R_MIN_));
      key = fmaxf(key, 0.f);
      int idx = (int)(key + 0.5f);
      if (idx > TBL-1) idx = TBL-1;
      int2 rec = make_int2(((s & (CHUNK-1)) << 17) | tgt[e], idx);
      ntstore_i2(&eb[lbase[c] + r], rec);
    }
  }
}

// ---------------- pass 2: fine scatter; builds offs ----------------
__global__ void k_fine(const int* __restrict__ cbase, const int2* __restrict__ eb,
                       int2* __restrict__ ep, int* __restrict__ offs){
  __shared__ int lcnt[CHUNK];
  __shared__ int lsc[CHUNK];
  int c = blockIdx.x;
  int t = threadIdx.x;                    // 512 threads
  int n0 = c * CHUNK;
  int n1 = min(n0 + CHUNK, NNODES);
  int cnt = n1 - n0;
  int j0 = cbase[c], j1 = cbase[c+1];
  lcnt[t] = 0;
  __syncthreads();
  for (int e = j0 + t; e < j1; e += 512){
    int2 rec = ntload_i2(&eb[e]);
    atomicAdd(&lcnt[((unsigned)rec.x) >> 17], 1);
  }
  __syncthreads();
  lsc[t] = lcnt[t];
  __syncthreads();
  for (int d = 1; d < 512; d <<= 1){
    int v = (t >= d) ? lsc[t-d] : 0;
    __syncthreads();
    lsc[t] += v;
    __syncthreads();
  }
  int excl = lsc[t] - lcnt[t];
  if (t < cnt) offs[n0 + t] = j0 + excl;
  __syncthreads();
  lcnt[t] = j0 + excl;                    // reuse as cursors
  __syncthreads();
  for (int e = j0 + t; e < j1; e += 512){
    int2 rec = ntload_i2(&eb[e]);
    int sl = ((unsigned)rec.x) >> 17;
    int pos = atomicAdd(&lcnt[sl], 1);
    ep[pos] = make_int2(rec.x & 0x1FFFF, rec.y);
  }
}

// ---------------- Gaussian table, fp16, nearest-neighbor ----------------
__global__ void k_gauss(const float* __restrict__ Wf, const float* __restrict__ bf,
                        const float* __restrict__ Ws, const float* __restrict__ bs,
                        __half* __restrict__ Gth){
  __shared__ float attr[64];
  int bi = blockIdx.x;                  // 3*TBL
  int i = bi / TBL, r = bi % TBL;
  int t = threadIdx.x;                  // 128
  float d = R_MIN_ + (R_MAX_-R_MIN_) * (float)r / (float)(TBL-1);
  if (t < 64){
    float cj = 1.f + 5.f * (float)t / 63.f;
    float u = (d - cj) * (64.f/5.f);
    attr[t] = __expf(-0.5f*u*u);
  }
  __syncthreads();
  int c = t >> 1;
  int side = t & 1;
  const float* W = (side ? Ws : Wf) + i*192*64 + 128*64 + c;
  float acc = (side ? bs : bf)[i*64 + c];
  #pragma unroll 8
  for (int j = 0; j < 64; j++) acc = fmaf(attr[j], W[j*64], acc);
  Gth[((size_t)i*TBL + r)*128 + t] = __float2half_rn(acc);
}

// ---------------- Wcat pack ----------------
__global__ void k_wcat(const float* __restrict__ Wf, const float* __restrict__ Ws,
                       float* __restrict__ Wcat){
  int idx = blockIdx.x*256 + threadIdx.x;
  if (idx >= 3*64*256) return;
  int i = idx / (64*256);
  int rem = idx % (64*256);
  int k = rem / 256, c = rem % 256;
  float v;
  if (c < 128){
    int p = c >> 1; bool ss = (c & 1);
    v = (ss ? Ws : Wf)[i*192*64 + k*64 + p];
  } else {
    int p = (c-128) >> 1; bool ss = (c & 1);
    v = (ss ? Ws : Wf)[i*192*64 + (64+k)*64 + p];
  }
  Wcat[i*64*256 + k*256 + c] = v;
}

// ---------------- layer-0 node transform fused with embedding gather ----------------
__global__ void k_ntrans0(const int* __restrict__ numbers, const float* __restrict__ embed,
                          const float* __restrict__ Wc, __half2* __restrict__ pqh,
                          float* __restrict__ x){
  __shared__ float xs[32*64];       // 8 KB
  int n0 = blockIdx.x * 32;         // 3125 blocks exact
  int t = threadIdx.x;              // 256
  #pragma unroll
  for (int i = 0; i < 2; i++){
    int flat = t + i*256;           // [0,512): 32 nodes x 16 float4
    int nn = flat >> 4, j = flat & 15;
    int num = numbers[n0 + nn];
    float4 v = ((const float4*)embed)[num*16 + j];
    ((float4*)xs)[flat] = v;
    ((float4*)(x + (size_t)n0*64))[flat] = v;
  }
  __syncthreads();
  int cg = t & 63, ng = t >> 6;
  float4 acc[8];
  #pragma unroll
  for (int i = 0; i < 8; i++) acc[i] = make_float4(0.f,0.f,0.f,0.f);
  const float* wp = Wc + 4*cg;
  const float* xp = xs + ng*8*64;
  #pragma unroll 2
  for (int k = 0; k < 64; k += 4){
    float4 w0 = *(const float4*)(wp + (k+0)*256);
    float4 w1 = *(const float4*)(wp + (k+1)*256);
    float4 w2 = *(const float4*)(wp + (k+2)*256);
    float4 w3 = *(const float4*)(wp + (k+3)*256);
    #pragma unroll
    for (int nn = 0; nn < 8; nn++){
      float4 xv = *(const float4*)(xp + nn*64 + k);
      fma4(acc[nn], xv.x, w0); fma4(acc[nn], xv.y, w1);
      fma4(acc[nn], xv.z, w2); fma4(acc[nn], xv.w, w3);
    }
  }
  #pragma unroll
  for (int nn = 0; nn < 8; nn++){
    int node = n0 + ng*8 + nn;
    __half2 h0 = __float22half2_rn(make_float2(acc[nn].x, acc[nn].y));
    __half2 h1 = __float22half2_rn(make_float2(acc[nn].z, acc[nn].w));
    __half2* dst = pqh + (size_t)node*128 + 2*cg;
    dst[0] = h0; dst[1] = h1;
  }
}

// ---------------- node transform (layers 1,2): 32 nodes x 256 cols ----------------
__global__ void k_ntrans(const float* __restrict__ x, const float* __restrict__ Wc,
                         __half2* __restrict__ pqh){
  __shared__ float xs[32*64];       // 8 KB
  int n0 = blockIdx.x * 32;         // 3125 blocks exact
  int t = threadIdx.x;              // 256
  ((float4*)xs)[t]       = ((const float4*)(x + (size_t)n0*64))[t];
  ((float4*)xs)[t + 256] = ((const float4*)(x + (size_t)n0*64))[t + 256];
  __syncthreads();
  int cg = t & 63, ng = t >> 6;
  float4 acc[8];
  #pragma unroll
  for (int i = 0; i < 8; i++) acc[i] = make_float4(0.f,0.f,0.f,0.f);
  const float* wp = Wc + 4*cg;
  const float* xp = xs + ng*8*64;
  #pragma unroll 2
  for (int k = 0; k < 64; k += 4){
    float4 w0 = *(const float4*)(wp + (k+0)*256);
    float4 w1 = *(const float4*)(wp + (k+1)*256);
    float4 w2 = *(const float4*)(wp + (k+2)*256);
    float4 w3 = *(const float4*)(wp + (k+3)*256);
    #pragma unroll
    for (int nn = 0; nn < 8; nn++){
      float4 xv = *(const float4*)(xp + nn*64 + k);
      fma4(acc[nn], xv.x, w0); fma4(acc[nn], xv.y, w1);
      fma4(acc[nn], xv.z, w2); fma4(acc[nn], xv.w, w3);
    }
  }
  #pragma unroll
  for (int nn = 0; nn < 8; nn++){
    int node = n0 + ng*8 + nn;
    __half2 h0 = __float22half2_rn(make_float2(acc[nn].x, acc[nn].y));
    __half2 h1 = __float22half2_rn(make_float2(acc[nn].z, acc[nn].w));
    __half2* dst = pqh + (size_t)node*128 + 2*cg;
    dst[0] = h0; dst[1] = h1;
  }
}

// ---------------- edge pass: wave per node, NN table, nt metadata ----------------
__global__ void k_edge(const __half2* __restrict__ pqh,
                       const int* __restrict__ offs, const int2* __restrict__ ep,
                       const __half* __restrict__ Gth, const float* __restrict__ lng,
                       const float* __restrict__ lnb, float* __restrict__ x){
  int wid  = (blockIdx.x*256 + threadIdx.x) >> 6;
  int lane = threadIdx.x & 63;
  int n = wid;
  int j0 = __builtin_amdgcn_readfirstlane(offs[n]);
  int j1 = __builtin_amdgcn_readfirstlane(offs[n+1]);
  int nfull = (j1 - j0) >> 3;
  int2 eb8[8];
  if (nfull > 0){
    #pragma unroll
    for (int i = 0; i < 8; i++) eb8[i] = ntload_i2(&ep[j0 + i]);
  }
  float2 pp = __half22float2(pqh[(size_t)n*128 + lane]);
  float acc = 0.f;
  int u = j0;
  for (int b = 0; b < nfull; b++){
    int tgv[8], idxv[8];
    #pragma unroll
    for (int i = 0; i < 8; i++){ tgv[i] = eb8[i].x; idxv[i] = eb8[i].y; }
    __half2 qr[8], gr[8];
    #pragma unroll
    for (int i = 0; i < 8; i++){
      qr[i] = pqh[(size_t)tgv[i]*128 + 64 + lane];
      gr[i] = *(const __half2*)(Gth + (size_t)idxv[i]*128 + 2*lane);
    }
    if (b + 1 < nfull){
      #pragma unroll
      for (int i = 0; i < 8; i++) eb8[i] = ntload_i2(&ep[u + 8 + i]);
    }
    #pragma unroll
    for (int i = 0; i < 8; i++){
      float2 qf = __half22float2(qr[i]);
      float2 gf = __half22float2(gr[i]);
      float zf = pp.x + qf.x + gf.x;
      float zs = pp.y + qf.y + gf.y;
      acc = fmaf(sigmoid_f(zf), softplus_f(zs), acc);
    }
    u += 8;
  }
  for (; u < j1; u++){
    int2 e = ep[u];
    float2 qf = __half22float2(pqh[(size_t)e.x*128 + 64 + lane]);
    float2 gf = __half22float2(*(const __half2*)(Gth + (size_t)e.y*128 + 2*lane));
    acc = fmaf(sigmoid_f(pp.x + qf.x + gf.x), softplus_f(pp.y + qf.y + gf.y), acc);
  }
  float s1 = acc, s2 = acc*acc;
  #pragma unroll
  for (int o = 32; o > 0; o >>= 1){ s1 += __shfl_xor(s1, o, 64); s2 += __shfl_xor(s2, o, 64); }
  float mu  = s1 * (1.f/64.f);
  float var = s2 * (1.f/64.f) - mu*mu;
  float inv = rsqrtf(fmaxf(var, 0.f) + 1e-5f);
  float y = (acc - mu) * inv * lng[lane] + lnb[lane];
  x[(size_t)n*64 + lane] += y;
}

// ---------------- fused head: LDS-tiled cooperative weight staging ----------------
__global__ void k_head(const float* __restrict__ x,
                       const float* __restrict__ W1, const float* __restrict__ b1,
                       const float* __restrict__ g1, const float* __restrict__ bt1,
                       const float* __restrict__ W2, const float* __restrict__ b2,
                       const float* __restrict__ g2, const float* __restrict__ bt2,
                       const float* __restrict__ Wout, const int* __restrict__ batch,
                       float* gsum, int* gcnt){
  __shared__ float xs[32*64];       // 8 KB
  __shared__ float hs[32*128];      // 16 KB
  __shared__ float wst[32*128];     // 16 KB weight tile (40 KB total -> 4 blocks/CU)
  __shared__ float es[32];
  int n0 = blockIdx.x * 32;         // 3125 blocks
  int t = threadIdx.x;              // 256
  ((float4*)xs)[t]       = ((const float4*)(x + (size_t)n0*64))[t];
  ((float4*)xs)[t + 256] = ((const float4*)(x + (size_t)n0*64))[t + 256];
  __syncthreads();
  int cg = t & 31, ng = t >> 5;     // 32 col-groups x 4 cols; 8 node-groups x 4 nodes

  // ---- layer 1: 64 -> 128, weights staged in 32-row tiles ----
  {
    float4 acc[4];
    #pragma unroll
    for (int i = 0; i < 4; i++) acc[i] = make_float4(0.f,0.f,0.f,0.f);
    const float* xp = xs + ng*4*64;
    for (int k0 = 0; k0 < 64; k0 += 32){
      #pragma unroll
      for (int j = 0; j < 4; j++)
        ((float4*)wst)[t + j*256] = ((const float4*)W1)[k0*32 + t + j*256];
      __syncthreads();
      #pragma unroll 4
      for (int kk = 0; kk < 32; kk += 4){
        float4 w0 = ((const float4*)wst)[(kk+0)*32 + cg];
        float4 w1 = ((const float4*)wst)[(kk+1)*32 + cg];
        float4 w2 = ((const float4*)wst)[(kk+2)*32 + cg];
        float4 w3 = ((const float4*)wst)[(kk+3)*32 + cg];
        #pragma unroll
        for (int nn = 0; nn < 4; nn++){
          float4 xv = *(const float4*)(xp + nn*64 + k0 + kk);
          fma4(acc[nn], xv.x, w0); fma4(acc[nn], xv.y, w1);
          fma4(acc[nn], xv.z, w2); fma4(acc[nn], xv.w, w3);
        }
      }
      __syncthreads();
    }
    float4 bv  = *(const float4*)(b1  + 4*cg);
    float4 gv  = *(const float4*)(g1  + 4*cg);
    float4 btv = *(const float4*)(bt1 + 4*cg);
    #pragma unroll
    for (int nn = 0; nn < 4; nn++){
      float4 v = acc[nn];
      v.x += bv.x; v.y += bv.y; v.z += bv.z; v.w += bv.w;
      float s1 = v.x + v.y + v.z + v.w;
      float s2 = v.x*v.x + v.y*v.y + v.z*v.z + v.w*v.w;
      #pragma unroll
      for (int o = 16; o > 0; o >>= 1){ s1 += __shfl_xor(s1, o, 64); s2 += __shfl_xor(s2, o, 64); }
      float mu  = s1 * (1.f/128.f);
      float var = s2 * (1.f/128.f) - mu*mu;
      float inv = rsqrtf(fmaxf(var, 0.f) + 1e-5f);
      float4 o4;
      o4.x = softplus_f((v.x - mu)*inv*gv.x + btv.x);
      o4.y = softplus_f((v.y - mu)*inv*gv.y + btv.y);
      o4.z = softplus_f((v.z - mu)*inv*gv.z + btv.z);
      o4.w = softplus_f((v.w - mu)*inv*gv.w + btv.w);
      *(float4*)(hs + (ng*4 + nn)*128 + 4*cg) = o4;
    }
  }
  __syncthreads();

  // ---- layer 2: 128 -> 128, weights staged in 32-row tiles ----
  {
    float4 acc[4];
    #pragma unroll
    for (int i = 0; i < 4; i++) acc[i] = make_float4(0.f,0.f,0.f,0.f);
    const float* hp = hs + ng*4*128;
    for (int k0 = 0; k0 < 128; k0 += 32){
      #pragma unroll
      for (int j = 0; j < 4; j++)
        ((float4*)wst)[t + j*256] = ((const float4*)W2)[k0*32 + t + j*256];
      __syncthreads();
      #pragma unroll 4
      for (int kk = 0; kk < 32; kk += 4){
        float4 w0 = ((const float4*)wst)[(kk+0)*32 + cg];
        float4 w1 = ((const float4*)wst)[(kk+1)*32 + cg];
        float4 w2 = ((const float4*)wst)[(kk+2)*32 + cg];
        float4 w3 = ((const float4*)wst)[(kk+3)*32 + cg];
        #pragma unroll
        for (int nn = 0; nn < 4; nn++){
          float4 hv = *(const float4*)(hp + nn*128 + k0 + kk);
          fma4(acc[nn], hv.x, w0); fma4(acc[nn], hv.y, w1);
          fma4(acc[nn], hv.z, w2); fma4(acc[nn], hv.w, w3);
        }
      }
      __syncthreads();
    }
    float4 bv  = *(const float4*)(b2  + 4*cg);
    float4 gv  = *(const float4*)(g2  + 4*cg);
    float4 btv = *(const float4*)(bt2 + 4*cg);
    float4 wo  = *(const float4*)(Wout + 4*cg);
    #pragma unroll
    for (int nn = 0; nn < 4; nn++){
      float4 v = acc[nn];
      v.x += bv.x; v.y += bv.y; v.z += bv.z; v.w += bv.w;
      float s1 = v.x + v.y + v.z + v.w;
      float s2 = v.x*v.x + v.y*v.y + v.z*v.z + v.w*v.w;
      #pragma unroll
      for (int o = 16; o > 0; o >>= 1){ s1 += __shfl_xor(s1, o, 64); s2 += __shfl_xor(s2, o, 64); }
      float mu  = s1 * (1.f/128.f);
      float var = s2 * (1.f/128.f) - mu*mu;
      float inv = rsqrtf(fmaxf(var, 0.f) + 1e-5f);
      float ev = softplus_f((v.x - mu)*inv*gv.x + btv.x) * wo.x
               + softplus_f((v.y - mu)*inv*gv.y + btv.y) * wo.y
               + softplus_f((v.z - mu)*inv*gv.z + btv.z) * wo.z
               + softplus_f((v.w - mu)*inv*gv.w + btv.w) * wo.w;
      #pragma unroll
      for (int o = 16; o > 0; o >>= 1) ev += __shfl_xor(ev, o, 64);
      if (cg == 0) es[ng*4 + nn] = ev;
    }
  }
  __syncthreads();

  // ---- segmented reduction over the sorted 32-node tile ----
  if (t < 32){
    int node = n0 + t;
    int g = batch[node];
    bool head = (t == 0) || (batch[node-1] != g);
    if (head){
      float s = 0.f; int c = 0;
      int j = t;
      while (j < 32 && batch[n0+j] == g){ s += es[j]; c++; j++; }
      atomicAdd(&gsum[g], s);
      atomicAdd(&gcnt[g], c);
    }
  }
}

// ---------------- final ----------------
__global__ void k_final(const float* __restrict__ gsum, const int* __restrict__ gcnt,
                        const float* __restrict__ bout, float* __restrict__ out){
  int g = threadIdx.x;
  if (g < NGRAPH)
    out[g] = gsum[g] / fmaxf((float)gcnt[g], 1.f) + bout[0];
}

extern "C" void kernel_launch(void* const* d_in, const int* in_sizes, int n_in,
                              void* d_out, int out_size, void* d_ws, size_t ws_size,
                              hipStream_t stream){
  const int*   numbers = (const int*)d_in[0];
  const int*   eidx    = (const int*)d_in[1];
  const float* elen    = (const float*)d_in[2];
  const int*   batch   = (const int*)d_in[3];
  const float* embed   = (const float*)d_in[4];
  const float* Wf      = (const float*)d_in[5];
  const float* bf      = (const float*)d_in[6];
  const float* Ws      = (const float*)d_in[7];
  const float* bs      = (const float*)d_in[8];
  const float* lng     = (const float*)d_in[9];
  const float* lnb     = (const float*)d_in[10];
  const float* W1      = (const float*)d_in[11];
  const float* b1      = (const float*)d_in[12];
  const float* g1      = (const float*)d_in[13];
  const float* bt1     = (const float*)d_in[14];
  const float* W2      = (const float*)d_in[15];
  const float* b2      = (const float*)d_in[16];
  const float* g2      = (const float*)d_in[17];
  const float* bt2     = (const float*)d_in[18];
  const float* Wout    = (const float*)d_in[19];
  const float* bout    = (const float*)d_in[20];
  const int* src = eidx;
  const int* tgt = eidx + NEDGES;

  float*   x    = (float*)d_ws;                          // N*64 f32
  __half2* pqh  = (__half2*)(x + (size_t)NNODES*64);     // N*128 half2
  __half*  Gth  = (__half*)(pqh + (size_t)NNODES*128);   // 3*TBL*128 half
  float*   Wcat = (float*)(Gth + (size_t)3*TBL*128);     // 3*64*256 f32
  int2*    ep   = (int2*)(Wcat + (size_t)3*64*256);      // E int2 (final CSR)
  int2*    ebuf = ep + NEDGES;                           // E int2 (staging)
  int*     offs = (int*)(ebuf + NEDGES);                 // N+1
  int*     ccnt = offs + NNODES + 1;                     // 256
  int*     cbase= ccnt + 256;                            // 256 (197 used)
  int*     ccur = cbase + 256;                           // 256
  float*   gsum = (float*)(ccur + 256);                  // 256
  int*     gcnt = (int*)(gsum + NGRAPH);                 // 256
  float*   out  = (float*)d_out;

  k_init  <<<(NNODES+255)/256, 256, 0, stream>>>(ccnt, gsum, gcnt);

  k_cnt   <<<(NEDGES+2047)/2048, 256, 0, stream>>>(src, ccnt);
  k_cscan <<<1, 256, 0, stream>>>(ccnt, cbase, ccur, offs);
  k_bin   <<<(NEDGES+2047)/2048, 256, 0, stream>>>(src, tgt, elen, ccur, ebuf);
  k_fine  <<<NCHUNK, 512, 0, stream>>>(cbase, ebuf, ep, offs);

  k_gauss <<<3*TBL, 128, 0, stream>>>(Wf, bf, Ws, bs, Gth);
  k_wcat  <<<(3*64*256+255)/256, 256, 0, stream>>>(Wf, Ws, Wcat);

  // layer 0: embed + ntrans fused
  k_ntrans0<<<NNODES/32, 256, 0, stream>>>(numbers, embed, Wcat, pqh, x);
  k_edge   <<<NNODES/4, 256, 0, stream>>>(pqh, offs, ep, Gth, lng, lnb, x);

  // layers 1,2
  for (int i = 1; i < NCONV; i++){
    k_ntrans<<<NNODES/32, 256, 0, stream>>>(x, Wcat + (size_t)i*64*256, pqh);
    k_edge  <<<NNODES/4, 256, 0, stream>>>(pqh, offs, ep,
                                           Gth + (size_t)i*TBL*128,
                                           lng + i*64, lnb + i*64, x);
  }

  k_head<<<NNODES/32, 256, 0, stream>>>(x, W1, b1, g1, bt1,
                                        W2, b2, g2, bt2, Wout, batch, gsum, gcnt);
  k_final<<<1, 256, 0, stream>>>(gsum, gcnt, bout, out);
}

// Round 17
// 807.106 us; speedup vs baseline: 1.0348x; 1.0348x over previous
//
#include <hip/hip_runtime.h>
#include <hip/hip_fp16.h>
#include <math.h>

#define NNODES 100000
#define NEDGES 1600000
#define NGRAPH 256
#define NCONV  3
#define TBL    4096
#define CHUNK  512
#define NCHUNK 196         // ceil(100000/512)
#define R_MIN_ 1.0f
#define R_MAX_ 6.0f

typedef float v2f __attribute__((ext_vector_type(2)));

__device__ __forceinline__ float softplus_f(float x){
  return fmaxf(x, 0.f) + __logf(1.f + __expf(-fabsf(x)));
}
__device__ __forceinline__ float sigmoid_f(float x){
  return __builtin_amdgcn_rcpf(1.f + __expf(-x));
}
__device__ __forceinline__ void fma4(float4& a, float s, const float4 w){
  a.x = fmaf(s, w.x, a.x); a.y = fmaf(s, w.y, a.y);
  a.z = fmaf(s, w.z, a.z); a.w = fmaf(s, w.w, a.w);
}
// nontemporal int2 via 64-bit scalar (builtin rejects HIP_vector_type)
__device__ __forceinline__ int2 ntload_i2(const int2* p){
  long long v = __builtin_nontemporal_load((const long long*)p);
  int2 r; r.x = (int)(unsigned)(v & 0xffffffffLL); r.y = (int)(v >> 32);
  return r;
}
__device__ __forceinline__ void ntstore_i2(int2* p, int2 v){
  long long w = (long long)(unsigned)v.x | ((long long)v.y << 32);
  __builtin_nontemporal_store(w, (long long*)p);
}

// ---------------- init: zero chunk counters + graph accumulators ----------------
__global__ void k_init(int* ccnt, float* gsum, int* gcnt){
  int i = blockIdx.x*256 + threadIdx.x;
  if (i < 256) ccnt[i] = 0;
  if (i < NGRAPH){ gsum[i] = 0.f; gcnt[i] = 0; }
}

// ---------------- chunk count ----------------
__global__ void k_cnt(const int* __restrict__ src, int* ccnt){
  __shared__ int l[NCHUNK];
  int t = threadIdx.x;
  int e0 = blockIdx.x * 2048;
  if (t < NCHUNK) l[t] = 0;
  __syncthreads();
  #pragma unroll
  for (int k = 0; k < 8; k++){
    int e = e0 + k*256 + t;
    if (e < NEDGES) atomicAdd(&l[src[e] / CHUNK], 1);
  }
  __syncthreads();
  if (t < NCHUNK && l[t] > 0) atomicAdd(&ccnt[t], l[t]);
}

// ---------------- chunk scan ----------------
__global__ void k_cscan(const int* __restrict__ ccnt, int* __restrict__ cbase,
                        int* __restrict__ ccur, int* __restrict__ offs){
  int t = threadIdx.x;
  if (t == 0){
    int run = 0;
    for (int c = 0; c < NCHUNK; c++){ cbase[c] = run; run += ccnt[c]; }
    cbase[NCHUNK] = NEDGES;
    offs[NNODES] = NEDGES;
  }
  __syncthreads();
  if (t < NCHUNK) ccur[t] = cbase[t];
}

// ---------------- pass 1: bin edges by 512-node chunk ----------------
__global__ void k_bin(const int* __restrict__ src, const int* __restrict__ tgt,
                      const float* __restrict__ elen, int* ccur,
                      int2* __restrict__ eb){
  __shared__ int lcnt[NCHUNK];
  __shared__ int lbase[NCHUNK];
  __shared__ int loff[NCHUNK];
  int t = threadIdx.x;
  int e0 = blockIdx.x * 2048;
  if (t < NCHUNK){ lcnt[t] = 0; loff[t] = 0; }
  __syncthreads();
  #pragma unroll
  for (int k = 0; k < 8; k++){
    int e = e0 + k*256 + t;
    if (e < NEDGES) atomicAdd(&lcnt[src[e] / CHUNK], 1);
  }
  __syncthreads();
  if (t < NCHUNK && lcnt[t] > 0) lbase[t] = atomicAdd(&ccur[t], lcnt[t]);
  __syncthreads();
  #pragma unroll
  for (int k = 0; k < 8; k++){
    int e = e0 + k*256 + t;
    if (e < NEDGES){
      int s = src[e];
      int c = s / CHUNK;
      int r = atomicAdd(&loff[c], 1);
      float key = (elen[e] - R_MIN_) * ((float)(TBL-1)/(R_MAX_-R_MIN_));
      key = fmaxf(key, 0.f);
      int idx = (int)(key + 0.5f);
      if (idx > TBL-1) idx = TBL-1;
      int2 rec = make_int2(((s & (CHUNK-1)) << 17) | tgt[e], idx);
      ntstore_i2(&eb[lbase[c] + r], rec);
    }
  }
}

// ---------------- pass 2: fine scatter; builds offs ----------------
__global__ void k_fine(const int* __restrict__ cbase, const int2* __restrict__ eb,
                       int2* __restrict__ ep, int* __restrict__ offs){
  __shared__ int lcnt[CHUNK];
  __shared__ int lsc[CHUNK];
  int c = blockIdx.x;
  int t = threadIdx.x;                    // 512 threads
  int n0 = c * CHUNK;
  int n1 = min(n0 + CHUNK, NNODES);
  int cnt = n1 - n0;
  int j0 = cbase[c], j1 = cbase[c+1];
  lcnt[t] = 0;
  __syncthreads();
  for (int e = j0 + t; e < j1; e += 512){
    int2 rec = ntload_i2(&eb[e]);
    atomicAdd(&lcnt[((unsigned)rec.x) >> 17], 1);
  }
  __syncthreads();
  lsc[t] = lcnt[t];
  __syncthreads();
  for (int d = 1; d < 512; d <<= 1){
    int v = (t >= d) ? lsc[t-d] : 0;
    __syncthreads();
    lsc[t] += v;
    __syncthreads();
  }
  int excl = lsc[t] - lcnt[t];
  if (t < cnt) offs[n0 + t] = j0 + excl;
  __syncthreads();
  lcnt[t] = j0 + excl;                    // reuse as cursors
  __syncthreads();
  for (int e = j0 + t; e < j1; e += 512){
    int2 rec = ntload_i2(&eb[e]);
    int sl = ((unsigned)rec.x) >> 17;
    int pos = atomicAdd(&lcnt[sl], 1);
    ep[pos] = make_int2(rec.x & 0x1FFFF, rec.y);
  }
}

// ---------------- Gaussian table, fp16, nearest-neighbor ----------------
__global__ void k_gauss(const float* __restrict__ Wf, const float* __restrict__ bf,
                        const float* __restrict__ Ws, const float* __restrict__ bs,
                        __half* __restrict__ Gth){
  __shared__ float attr[64];
  int bi = blockIdx.x;                  // 3*TBL
  int i = bi / TBL, r = bi % TBL;
  int t = threadIdx.x;                  // 128
  float d = R_MIN_ + (R_MAX_-R_MIN_) * (float)r / (float)(TBL-1);
  if (t < 64){
    float cj = 1.f + 5.f * (float)t / 63.f;
    float u = (d - cj) * (64.f/5.f);
    attr[t] = __expf(-0.5f*u*u);
  }
  __syncthreads();
  int c = t >> 1;
  int side = t & 1;
  const float* W = (side ? Ws : Wf) + i*192*64 + 128*64 + c;
  float acc = (side ? bs : bf)[i*64 + c];
  #pragma unroll 8
  for (int j = 0; j < 64; j++) acc = fmaf(attr[j], W[j*64], acc);
  Gth[((size_t)i*TBL + r)*128 + t] = __float2half_rn(acc);
}

// ---------------- Wcat pack ----------------
__global__ void k_wcat(const float* __restrict__ Wf, const float* __restrict__ Ws,
                       float* __restrict__ Wcat){
  int idx = blockIdx.x*256 + threadIdx.x;
  if (idx >= 3*64*256) return;
  int i = idx / (64*256);
  int rem = idx % (64*256);
  int k = rem / 256, c = rem % 256;
  float v;
  if (c < 128){
    int p = c >> 1; bool ss = (c & 1);
    v = (ss ? Ws : Wf)[i*192*64 + k*64 + p];
  } else {
    int p = (c-128) >> 1; bool ss = (c & 1);
    v = (ss ? Ws : Wf)[i*192*64 + (64+k)*64 + p];
  }
  Wcat[i*64*256 + k*256 + c] = v;
}

// ---------------- layer-0 node transform fused with embedding gather ----------------
// p (cols 0..127) -> ph, q (cols 128..255) -> qh : separate arrays so the
// edge gather's random footprint is 25.6 MB, not 51 MB.
__global__ void k_ntrans0(const int* __restrict__ numbers, const float* __restrict__ embed,
                          const float* __restrict__ Wc, __half2* __restrict__ ph,
                          __half2* __restrict__ qh, float* __restrict__ x){
  __shared__ float xs[32*64];       // 8 KB
  int n0 = blockIdx.x * 32;         // 3125 blocks exact
  int t = threadIdx.x;              // 256
  #pragma unroll
  for (int i = 0; i < 2; i++){
    int flat = t + i*256;           // [0,512): 32 nodes x 16 float4
    int nn = flat >> 4, j = flat & 15;
    int num = numbers[n0 + nn];
    float4 v = ((const float4*)embed)[num*16 + j];
    ((float4*)xs)[flat] = v;
    ((float4*)(x + (size_t)n0*64))[flat] = v;
  }
  __syncthreads();
  int cg = t & 63, ng = t >> 6;
  float4 acc[8];
  #pragma unroll
  for (int i = 0; i < 8; i++) acc[i] = make_float4(0.f,0.f,0.f,0.f);
  const float* wp = Wc + 4*cg;
  const float* xp = xs + ng*8*64;
  #pragma unroll 2
  for (int k = 0; k < 64; k += 4){
    float4 w0 = *(const float4*)(wp + (k+0)*256);
    float4 w1 = *(const float4*)(wp + (k+1)*256);
    float4 w2 = *(const float4*)(wp + (k+2)*256);
    float4 w3 = *(const float4*)(wp + (k+3)*256);
    #pragma unroll
    for (int nn = 0; nn < 8; nn++){
      float4 xv = *(const float4*)(xp + nn*64 + k);
      fma4(acc[nn], xv.x, w0); fma4(acc[nn], xv.y, w1);
      fma4(acc[nn], xv.z, w2); fma4(acc[nn], xv.w, w3);
    }
  }
  #pragma unroll
  for (int nn = 0; nn < 8; nn++){
    int node = n0 + ng*8 + nn;
    __half2 h0 = __float22half2_rn(make_float2(acc[nn].x, acc[nn].y));
    __half2 h1 = __float22half2_rn(make_float2(acc[nn].z, acc[nn].w));
    __half2* dst = (cg < 32) ? (ph + (size_t)node*64 + 2*cg)
                             : (qh + (size_t)node*64 + 2*(cg-32));
    dst[0] = h0; dst[1] = h1;
  }
}

// ---------------- node transform (layers 1,2): 32 nodes x 256 cols ----------------
__global__ void k_ntrans(const float* __restrict__ x, const float* __restrict__ Wc,
                         __half2* __restrict__ ph, __half2* __restrict__ qh){
  __shared__ float xs[32*64];       // 8 KB
  int n0 = blockIdx.x * 32;         // 3125 blocks exact
  int t = threadIdx.x;              // 256
  ((float4*)xs)[t]       = ((const float4*)(x + (size_t)n0*64))[t];
  ((float4*)xs)[t + 256] = ((const float4*)(x + (size_t)n0*64))[t + 256];
  __syncthreads();
  int cg = t & 63, ng = t >> 6;
  float4 acc[8];
  #pragma unroll
  for (int i = 0; i < 8; i++) acc[i] = make_float4(0.f,0.f,0.f,0.f);
  const float* wp = Wc + 4*cg;
  const float* xp = xs + ng*8*64;
  #pragma unroll 2
  for (int k = 0; k < 64; k += 4){
    float4 w0 = *(const float4*)(wp + (k+0)*256);
    float4 w1 = *(const float4*)(wp + (k+1)*256);
    float4 w2 = *(const float4*)(wp + (k+2)*256);
    float4 w3 = *(const float4*)(wp + (k+3)*256);
    #pragma unroll
    for (int nn = 0; nn < 8; nn++){
      float4 xv = *(const float4*)(xp + nn*64 + k);
      fma4(acc[nn], xv.x, w0); fma4(acc[nn], xv.y, w1);
      fma4(acc[nn], xv.z, w2); fma4(acc[nn], xv.w, w3);
    }
  }
  #pragma unroll
  for (int nn = 0; nn < 8; nn++){
    int node = n0 + ng*8 + nn;
    __half2 h0 = __float22half2_rn(make_float2(acc[nn].x, acc[nn].y));
    __half2 h1 = __float22half2_rn(make_float2(acc[nn].z, acc[nn].w));
    __half2* dst = (cg < 32) ? (ph + (size_t)node*64 + 2*cg)
                             : (qh + (size_t)node*64 + 2*(cg-32));
    dst[0] = h0; dst[1] = h1;
  }
}

// ---------------- edge pass: wave per node, NN table, split p/q ----------------
__global__ void k_edge(const __half2* __restrict__ ph, const __half2* __restrict__ qh,
                       const int* __restrict__ offs, const int2* __restrict__ ep,
                       const __half* __restrict__ Gth, const float* __restrict__ lng,
                       const float* __restrict__ lnb, float* __restrict__ x){
  int wid  = (blockIdx.x*256 + threadIdx.x) >> 6;
  int lane = threadIdx.x & 63;
  int n = wid;
  int j0 = __builtin_amdgcn_readfirstlane(offs[n]);
  int j1 = __builtin_amdgcn_readfirstlane(offs[n+1]);
  int nfull = (j1 - j0) >> 3;
  int2 eb8[8];
  if (nfull > 0){
    #pragma unroll
    for (int i = 0; i < 8; i++) eb8[i] = ntload_i2(&ep[j0 + i]);
  }
  float2 pp = __half22float2(ph[(size_t)n*64 + lane]);
  float acc = 0.f;
  int u = j0;
  for (int b = 0; b < nfull; b++){
    int tgv[8], idxv[8];
    #pragma unroll
    for (int i = 0; i < 8; i++){ tgv[i] = eb8[i].x; idxv[i] = eb8[i].y; }
    __half2 qr[8], gr[8];
    #pragma unroll
    for (int i = 0; i < 8; i++){
      qr[i] = qh[(size_t)tgv[i]*64 + lane];
      gr[i] = *(const __half2*)(Gth + (size_t)idxv[i]*128 + 2*lane);
    }
    if (b + 1 < nfull){
      #pragma unroll
      for (int i = 0; i < 8; i++) eb8[i] = ntload_i2(&ep[u + 8 + i]);
    }
    #pragma unroll
    for (int i = 0; i < 8; i++){
      float2 qf = __half22float2(qr[i]);
      float2 gf = __half22float2(gr[i]);
      float zf = pp.x + qf.x + gf.x;
      float zs = pp.y + qf.y + gf.y;
      acc = fmaf(sigmoid_f(zf), softplus_f(zs), acc);
    }
    u += 8;
  }
  for (; u < j1; u++){
    int2 e = ep[u];
    float2 qf = __half22float2(qh[(size_t)e.x*64 + lane]);
    float2 gf = __half22float2(*(const __half2*)(Gth + (size_t)e.y*128 + 2*lane));
    acc = fmaf(sigmoid_f(pp.x + qf.x + gf.x), softplus_f(pp.y + qf.y + gf.y), acc);
  }
  float s1 = acc, s2 = acc*acc;
  #pragma unroll
  for (int o = 32; o > 0; o >>= 1){ s1 += __shfl_xor(s1, o, 64); s2 += __shfl_xor(s2, o, 64); }
  float mu  = s1 * (1.f/64.f);
  float var = s2 * (1.f/64.f) - mu*mu;
  float inv = rsqrtf(fmaxf(var, 0.f) + 1e-5f);
  float y = (acc - mu) * inv * lng[lane] + lnb[lane];
  x[(size_t)n*64 + lane] += y;
}

// ---------------- fused head with K=8 register-prefetched weights (R15) ----------------
__global__ void k_head(const float* __restrict__ x,
                       const float* __restrict__ W1, const float* __restrict__ b1,
                       const float* __restrict__ g1, const float* __restrict__ bt1,
                       const float* __restrict__ W2, const float* __restrict__ b2,
                       const float* __restrict__ g2, const float* __restrict__ bt2,
                       const float* __restrict__ Wout, const int* __restrict__ batch,
                       float* gsum, int* gcnt){
  __shared__ float xs[32*64];       // 8 KB
  __shared__ float hs[32*128];      // 16 KB
  __shared__ float es[32];
  int n0 = blockIdx.x * 32;         // 3125 blocks
  int t = threadIdx.x;              // 256
  ((float4*)xs)[t]       = ((const float4*)(x + (size_t)n0*64))[t];
  ((float4*)xs)[t + 256] = ((const float4*)(x + (size_t)n0*64))[t + 256];
  __syncthreads();
  int cg = t & 31, ng = t >> 5;

  // ---- layer 1: 64 -> 128, LN, softplus, into hs ----
  {
    float4 acc[4];
    #pragma unroll
    for (int i = 0; i < 4; i++) acc[i] = make_float4(0.f,0.f,0.f,0.f);
    const float* wp = W1 + 4*cg;
    const float* xp = xs + ng*4*64;
    float4 w[8];
    #pragma unroll
    for (int j = 0; j < 8; j++) w[j] = *(const float4*)(wp + j*128);
    for (int k = 0; k < 64; k += 8){
      float4 wn[8];
      int kn = (k + 8 < 64) ? k + 8 : 0;
      #pragma unroll
      for (int j = 0; j < 8; j++) wn[j] = *(const float4*)(wp + (kn+j)*128);
      #pragma unroll
      for (int h = 0; h < 2; h++){
        #pragma unroll
        for (int nn = 0; nn < 4; nn++){
          float4 xv = *(const float4*)(xp + nn*64 + k + h*4);
          fma4(acc[nn], xv.x, w[h*4+0]); fma4(acc[nn], xv.y, w[h*4+1]);
          fma4(acc[nn], xv.z, w[h*4+2]); fma4(acc[nn], xv.w, w[h*4+3]);
        }
      }
      #pragma unroll
      for (int j = 0; j < 8; j++) w[j] = wn[j];
    }
    float4 bv  = *(const float4*)(b1  + 4*cg);
    float4 gv  = *(const float4*)(g1  + 4*cg);
    float4 btv = *(const float4*)(bt1 + 4*cg);
    #pragma unroll
    for (int nn = 0; nn < 4; nn++){
      float4 v = acc[nn];
      v.x += bv.x; v.y += bv.y; v.z += bv.z; v.w += bv.w;
      float s1 = v.x + v.y + v.z + v.w;
      float s2 = v.x*v.x + v.y*v.y + v.z*v.z + v.w*v.w;
      #pragma unroll
      for (int o = 16; o > 0; o >>= 1){ s1 += __shfl_xor(s1, o, 64); s2 += __shfl_xor(s2, o, 64); }
      float mu  = s1 * (1.f/128.f);
      float var = s2 * (1.f/128.f) - mu*mu;
      float inv = rsqrtf(fmaxf(var, 0.f) + 1e-5f);
      float4 o4;
      o4.x = softplus_f((v.x - mu)*inv*gv.x + btv.x);
      o4.y = softplus_f((v.y - mu)*inv*gv.y + btv.y);
      o4.z = softplus_f((v.z - mu)*inv*gv.z + btv.z);
      o4.w = softplus_f((v.w - mu)*inv*gv.w + btv.w);
      *(float4*)(hs + (ng*4 + nn)*128 + 4*cg) = o4;
    }
  }
  __syncthreads();

  // ---- layer 2: 128 -> 128, LN, softplus, proj -> per-node energy ----
  {
    float4 acc[4];
    #pragma unroll
    for (int i = 0; i < 4; i++) acc[i] = make_float4(0.f,0.f,0.f,0.f);
    const float* wp = W2 + 4*cg;
    const float* hp = hs + ng*4*128;
    float4 w[8];
    #pragma unroll
    for (int j = 0; j < 8; j++) w[j] = *(const float4*)(wp + j*128);
    for (int k = 0; k < 128; k += 8){
      float4 wn[8];
      int kn = (k + 8 < 128) ? k + 8 : 0;
      #pragma unroll
      for (int j = 0; j < 8; j++) wn[j] = *(const float4*)(wp + (kn+j)*128);
      #pragma unroll
      for (int h = 0; h < 2; h++){
        #pragma unroll
        for (int nn = 0; nn < 4; nn++){
          float4 hv = *(const float4*)(hp + nn*128 + k + h*4);
          fma4(acc[nn], hv.x, w[h*4+0]); fma4(acc[nn], hv.y, w[h*4+1]);
          fma4(acc[nn], hv.z, w[h*4+2]); fma4(acc[nn], hv.w, w[h*4+3]);
        }
      }
      #pragma unroll
      for (int j = 0; j < 8; j++) w[j] = wn[j];
    }
    float4 bv  = *(const float4*)(b2  + 4*cg);
    float4 gv  = *(const float4*)(g2  + 4*cg);
    float4 btv = *(const float4*)(bt2 + 4*cg);
    float4 wo  = *(const float4*)(Wout + 4*cg);
    #pragma unroll
    for (int nn = 0; nn < 4; nn++){
      float4 v = acc[nn];
      v.x += bv.x; v.y += bv.y; v.z += bv.z; v.w += bv.w;
      float s1 = v.x + v.y + v.z + v.w;
      float s2 = v.x*v.x + v.y*v.y + v.z*v.z + v.w*v.w;
      #pragma unroll
      for (int o = 16; o > 0; o >>= 1){ s1 += __shfl_xor(s1, o, 64); s2 += __shfl_xor(s2, o, 64); }
      float mu  = s1 * (1.f/128.f);
      float var = s2 * (1.f/128.f) - mu*mu;
      float inv = rsqrtf(fmaxf(var, 0.f) + 1e-5f);
      float ev = softplus_f((v.x - mu)*inv*gv.x + btv.x) * wo.x
               + softplus_f((v.y - mu)*inv*gv.y + btv.y) * wo.y
               + softplus_f((v.z - mu)*inv*gv.z + btv.z) * wo.z
               + softplus_f((v.w - mu)*inv*gv.w + btv.w) * wo.w;
      #pragma unroll
      for (int o = 16; o > 0; o >>= 1) ev += __shfl_xor(ev, o, 64);
      if (cg == 0) es[ng*4 + nn] = ev;
    }
  }
  __syncthreads();

  // ---- segmented reduction over the sorted 32-node tile ----
  if (t < 32){
    int node = n0 + t;
    int g = batch[node];
    bool head = (t == 0) || (batch[node-1] != g);
    if (head){
      float s = 0.f; int c = 0;
      int j = t;
      while (j < 32 && batch[n0+j] == g){ s += es[j]; c++; j++; }
      atomicAdd(&gsum[g], s);
      atomicAdd(&gcnt[g], c);
    }
  }
}

// ---------------- final ----------------
__global__ void k_final(const float* __restrict__ gsum, const int* __restrict__ gcnt,
                        const float* __restrict__ bout, float* __restrict__ out){
  int g = threadIdx.x;
  if (g < NGRAPH)
    out[g] = gsum[g] / fmaxf((float)gcnt[g], 1.f) + bout[0];
}

extern "C" void kernel_launch(void* const* d_in, const int* in_sizes, int n_in,
                              void* d_out, int out_size, void* d_ws, size_t ws_size,
                              hipStream_t stream){
  const int*   numbers = (const int*)d_in[0];
  const int*   eidx    = (const int*)d_in[1];
  const float* elen    = (const float*)d_in[2];
  const int*   batch   = (const int*)d_in[3];
  const float* embed   = (const float*)d_in[4];
  const float* Wf      = (const float*)d_in[5];
  const float* bf      = (const float*)d_in[6];
  const float* Ws      = (const float*)d_in[7];
  const float* bs      = (const float*)d_in[8];
  const float* lng     = (const float*)d_in[9];
  const float* lnb     = (const float*)d_in[10];
  const float* W1      = (const float*)d_in[11];
  const float* b1      = (const float*)d_in[12];
  const float* g1      = (const float*)d_in[13];
  const float* bt1     = (const float*)d_in[14];
  const float* W2      = (const float*)d_in[15];
  const float* b2      = (const float*)d_in[16];
  const float* g2      = (const float*)d_in[17];
  const float* bt2     = (const float*)d_in[18];
  const float* Wout    = (const float*)d_in[19];
  const float* bout    = (const float*)d_in[20];
  const int* src = eidx;
  const int* tgt = eidx + NEDGES;

  float*   x    = (float*)d_ws;                          // N*64 f32
  __half2* ph   = (__half2*)(x + (size_t)NNODES*64);     // N*64 half2 (p, sequential)
  __half2* qh   = ph + (size_t)NNODES*64;                // N*64 half2 (q, gathered)
  __half*  Gth  = (__half*)(qh + (size_t)NNODES*64);     // 3*TBL*128 half
  float*   Wcat = (float*)(Gth + (size_t)3*TBL*128);     // 3*64*256 f32
  int2*    ep   = (int2*)(Wcat + (size_t)3*64*256);      // E int2 (final CSR)
  int2*    ebuf = ep + NEDGES;                           // E int2 (staging)
  int*     offs = (int*)(ebuf + NEDGES);                 // N+1
  int*     ccnt = offs + NNODES + 1;                     // 256
  int*     cbase= ccnt + 256;                            // 256 (197 used)
  int*     ccur = cbase + 256;                           // 256
  float*   gsum = (float*)(ccur + 256);                  // 256
  int*     gcnt = (int*)(gsum + NGRAPH);                 // 256
  float*   out  = (float*)d_out;

  k_init  <<<(NNODES+255)/256, 256, 0, stream>>>(ccnt, gsum, gcnt);

  k_cnt   <<<(NEDGES+2047)/2048, 256, 0, stream>>>(src, ccnt);
  k_cscan <<<1, 256, 0, stream>>>(ccnt, cbase, ccur, offs);
  k_bin   <<<(NEDGES+2047)/2048, 256, 0, stream>>>(src, tgt, elen, ccur, ebuf);
  k_fine  <<<NCHUNK, 512, 0, stream>>>(cbase, ebuf, ep, offs);

  k_gauss <<<3*TBL, 128, 0, stream>>>(Wf, bf, Ws, bs, Gth);
  k_wcat  <<<(3*64*256+255)/256, 256, 0, stream>>>(Wf, Ws, Wcat);

  // layer 0: embed + ntrans fused
  k_ntrans0<<<NNODES/32, 256, 0, stream>>>(numbers, embed, Wcat, ph, qh, x);
  k_edge   <<<NNODES/4, 256, 0, stream>>>(ph, qh, offs, ep, Gth, lng, lnb, x);

  // layers 1,2
  for (int i = 1; i < NCONV; i++){
    k_ntrans<<<NNODES/32, 256, 0, stream>>>(x, Wcat + (size_t)i*64*256, ph, qh);
    k_edge  <<<NNODES/4, 256, 0, stream>>>(ph, qh, offs, ep,
                                           Gth + (size_t)i*TBL*128,
                                           lng + i*64, lnb + i*64, x);
  }

  k_head<<<NNODES/32, 256, 0, stream>>>(x, W1, b1, g1, bt1,
                                        W2, b2, g2, bt2, Wout, batch, gsum, gcnt);
  k_final<<<1, 256, 0, stream>>>(gsum, gcnt, bout, out);
}